// Round 1
// baseline (400.491 us; speedup 1.0000x reference)
//
#include <hip/hip_runtime.h>
#include <hip/hip_bf16.h>

#define NN 100000
#define NE 800000

// ---------------- CSR build ----------------
static __global__ __launch_bounds__(256) void k_zero(int* __restrict__ p, int n) {
  int i = blockIdx.x * 256 + threadIdx.x;
  if (i < n) p[i] = 0;
}

static __global__ __launch_bounds__(256) void k_count(const int* __restrict__ dst, int* __restrict__ counts, int ne) {
  int e = blockIdx.x * 256 + threadIdx.x;
  if (e < ne) atomicAdd(&counts[dst[e]], 1);
}

static __global__ __launch_bounds__(256) void k_dis(const int* __restrict__ counts, float* __restrict__ dis, int n) {
  int i = blockIdx.x * 256 + threadIdx.x;
  if (i < n) dis[i] = 1.0f / sqrtf((float)counts[i] + 1.0f);  // deg = in-edges + self-loop
}

static __global__ __launch_bounds__(256) void k_scan1(const int* __restrict__ counts, int* __restrict__ rs,
                                                      int* __restrict__ blk, int n) {
  __shared__ int sd[256];
  int tid = threadIdx.x;
  int base = blockIdx.x * 1024 + tid * 4;
  int v0 = (base + 0 < n) ? counts[base + 0] : 0;
  int v1 = (base + 1 < n) ? counts[base + 1] : 0;
  int v2 = (base + 2 < n) ? counts[base + 2] : 0;
  int v3 = (base + 3 < n) ? counts[base + 3] : 0;
  int s = v0 + v1 + v2 + v3;
  sd[tid] = s;
  __syncthreads();
  for (int off = 1; off < 256; off <<= 1) {
    int t = (tid >= off) ? sd[tid - off] : 0;
    __syncthreads();
    sd[tid] += t;
    __syncthreads();
  }
  int excl = sd[tid] - s;
  if (base + 0 < n) rs[base + 0] = excl;
  if (base + 1 < n) rs[base + 1] = excl + v0;
  if (base + 2 < n) rs[base + 2] = excl + v0 + v1;
  if (base + 3 < n) rs[base + 3] = excl + v0 + v1 + v2;
  if (tid == 255) blk[blockIdx.x] = sd[255];
}

static __global__ void k_scan2(int* __restrict__ blk, int nb) {
  __shared__ int sd[128];
  int tid = threadIdx.x;
  sd[tid] = (tid < nb) ? blk[tid] : 0;
  __syncthreads();
  if (tid == 0) {
    int run = 0;
    for (int i = 0; i < nb; ++i) { int v = sd[i]; sd[i] = run; run += v; }
  }
  __syncthreads();
  if (tid < nb) blk[tid] = sd[tid];
}

static __global__ __launch_bounds__(256) void k_scan3(int* __restrict__ rs, const int* __restrict__ blk,
                                                      int* __restrict__ cursor, int n) {
  int i = blockIdx.x * 256 + threadIdx.x;
  if (i < n) {
    int v = rs[i] + blk[i >> 10];
    rs[i] = v;
    cursor[i] = v;
  }
}

static __global__ __launch_bounds__(256) void k_fill(const int* __restrict__ src, const int* __restrict__ dst,
                                                     int* __restrict__ cursor, int* __restrict__ col_idx, int ne) {
  int e = blockIdx.x * 256 + threadIdx.x;
  if (e < ne) {
    int d = dst[e];
    int pos = atomicAdd(&cursor[d], 1);
    col_idx[pos] = src[e];
  }
}

// ---------------- tiled 64x64 f32 matmul core ----------------
// At: A-tile transposed [feat][row], stride 132 (16B aligned rows, bank-spread)
// Ws: W row-major [64][64]
__device__ __forceinline__ void mm_tile(const float (*At)[132], const float (*Ws)[64],
                                        int r0, int c0, float acc[8][4]) {
#pragma unroll 4
  for (int k = 0; k < 64; ++k) {
    float4 w  = *(const float4*)&Ws[k][c0];
    float4 a0 = *(const float4*)&At[k][r0];
    float4 a1 = *(const float4*)&At[k][r0 + 4];
    float a_[8] = {a0.x, a0.y, a0.z, a0.w, a1.x, a1.y, a1.z, a1.w};
#pragma unroll
    for (int r = 0; r < 8; ++r) {
      acc[r][0] = fmaf(a_[r], w.x, acc[r][0]);
      acc[r][1] = fmaf(a_[r], w.y, acc[r][1]);
      acc[r][2] = fmaf(a_[r], w.z, acc[r][2]);
      acc[r][3] = fmaf(a_[r], w.w, acc[r][3]);
    }
  }
}

__device__ __forceinline__ void load_w(const float* __restrict__ W, float (*Ws)[64], int tid) {
  const float4* W4 = (const float4*)W;
  float4* Ws4 = (float4*)&Ws[0][0];
  Ws4[tid] = W4[tid];
  Ws4[tid + 256] = W4[tid + 256];
  Ws4[tid + 512] = W4[tid + 512];
  Ws4[tid + 768] = W4[tid + 768];
}

__device__ __forceinline__ void load_a_transposed(const float* __restrict__ in, float (*At)[132],
                                                  int row0, int n, int tid) {
#pragma unroll
  for (int i = 0; i < 8; ++i) {
    int idx = tid + 256 * i;      // 0..2047
    int r = idx >> 4, c4 = idx & 15;
    int grow = row0 + r;
    float4 v = make_float4(0.f, 0.f, 0.f, 0.f);
    if (grow < n) v = ((const float4*)in)[grow * 16 + c4];
    At[c4 * 4 + 0][r] = v.x;
    At[c4 * 4 + 1][r] = v.y;
    At[c4 * 4 + 2][r] = v.z;
    At[c4 * 4 + 3][r] = v.w;
  }
}

// ht[i][:] = (in[i][:] @ W) * dis[i]
static __global__ __launch_bounds__(256) void k_mm(const float* __restrict__ in, const float* __restrict__ W,
                                                   const float* __restrict__ dis, float* __restrict__ out, int n) {
  __shared__ float At[64][132];
  __shared__ float Ws[64][64];
  int tid = threadIdx.x;
  int row0 = blockIdx.x * 128;
  load_w(W, Ws, tid);
  load_a_transposed(in, At, row0, n, tid);
  __syncthreads();
  int col_t = tid & 15, row_t = tid >> 4;
  int c0 = col_t * 4, r0 = row_t * 8;
  float acc[8][4] = {};
  mm_tile(At, Ws, r0, c0, acc);
#pragma unroll
  for (int r = 0; r < 8; ++r) {
    int grow = row0 + r0 + r;
    if (grow < n) {
      float s = dis[grow];
      float4 o = make_float4(acc[r][0] * s, acc[r][1] * s, acc[r][2] * s, acc[r][3] * s);
      *(float4*)&out[grow * 64 + c0] = o;
    }
  }
}

// out[i][:] = relu(dis[i] * (ht[i][:] + sum_{s in N(i)} ht[s][:]) + b[:])
static __global__ __launch_bounds__(256) void k_agg(const float* __restrict__ ht, const int* __restrict__ rs,
                                                    const int* __restrict__ counts, const int* __restrict__ col_idx,
                                                    const float* __restrict__ dis, const float* __restrict__ bias,
                                                    float* __restrict__ out, int n) {
  int gw = (blockIdx.x * 256 + threadIdx.x) >> 6;   // node per wave
  int lane = threadIdx.x & 63;                      // feature
  if (gw >= n) return;
  float acc = ht[gw * 64 + lane];                   // self-loop
  int beg = rs[gw], cnt = counts[gw];
  for (int base = 0; base < cnt; base += 64) {
    int m = min(64, cnt - base);
    int idx = (base + lane < cnt) ? col_idx[beg + base + lane] : 0;
    for (int e = 0; e < m; ++e) {
      int s = __shfl(idx, e);
      acc += ht[s * 64 + lane];
    }
  }
  float v = dis[gw] * acc + bias[lane];
  out[gw * 64 + lane] = fmaxf(v, 0.f);
}

// fused: relu(h@Wf1+bf1) -> relu(@Wf2+bf2) -> @Wf3+bf3 -> log_softmax
static __global__ __launch_bounds__(256) void k_dense(const float* __restrict__ in,
    const float* __restrict__ Wf1, const float* __restrict__ bf1,
    const float* __restrict__ Wf2, const float* __restrict__ bf2,
    const float* __restrict__ Wf3, const float* __restrict__ bf3,
    float* __restrict__ out, int n) {
  __shared__ float At[64][132];
  __shared__ float Ws[64][64];
  int tid = threadIdx.x;
  int row0 = blockIdx.x * 128;
  load_w(Wf1, Ws, tid);
  load_a_transposed(in, At, row0, n, tid);
  __syncthreads();
  int col_t = tid & 15, row_t = tid >> 4;
  int c0 = col_t * 4, r0 = row_t * 8;
  float4 b1v = *(const float4*)&bf1[c0];
  float acc[8][4] = {};
  mm_tile(At, Ws, r0, c0, acc);
  __syncthreads();
  // h1 = relu(acc + bf1) -> At (transposed); stage Wf2
#pragma unroll
  for (int r = 0; r < 8; ++r) {
    At[c0 + 0][r0 + r] = fmaxf(acc[r][0] + b1v.x, 0.f);
    At[c0 + 1][r0 + r] = fmaxf(acc[r][1] + b1v.y, 0.f);
    At[c0 + 2][r0 + r] = fmaxf(acc[r][2] + b1v.z, 0.f);
    At[c0 + 3][r0 + r] = fmaxf(acc[r][3] + b1v.w, 0.f);
  }
  load_w(Wf2, Ws, tid);
  __syncthreads();
  float4 b2v = *(const float4*)&bf2[c0];
  float acc2[8][4] = {};
  mm_tile(At, Ws, r0, c0, acc2);
  __syncthreads();
#pragma unroll
  for (int r = 0; r < 8; ++r) {
    At[c0 + 0][r0 + r] = fmaxf(acc2[r][0] + b2v.x, 0.f);
    At[c0 + 1][r0 + r] = fmaxf(acc2[r][1] + b2v.y, 0.f);
    At[c0 + 2][r0 + r] = fmaxf(acc2[r][2] + b2v.z, 0.f);
    At[c0 + 3][r0 + r] = fmaxf(acc2[r][3] + b2v.w, 0.f);
  }
  __syncthreads();
  // z-phase: thread t<128 owns local row t; Wf3 reads are wave-uniform (scalarizable)
  if (tid < 128) {
    int grow = row0 + tid;
    if (grow < n) {
      float z[16];
#pragma unroll
      for (int j = 0; j < 16; ++j) z[j] = bf3[j];
      const float4* W3v = (const float4*)Wf3;
#pragma unroll 4
      for (int k = 0; k < 64; ++k) {
        float h = At[k][tid];
        float4 w0 = W3v[k * 4 + 0];
        float4 w1 = W3v[k * 4 + 1];
        float4 w2 = W3v[k * 4 + 2];
        float4 w3 = W3v[k * 4 + 3];
        z[0]  = fmaf(h, w0.x, z[0]);  z[1]  = fmaf(h, w0.y, z[1]);
        z[2]  = fmaf(h, w0.z, z[2]);  z[3]  = fmaf(h, w0.w, z[3]);
        z[4]  = fmaf(h, w1.x, z[4]);  z[5]  = fmaf(h, w1.y, z[5]);
        z[6]  = fmaf(h, w1.z, z[6]);  z[7]  = fmaf(h, w1.w, z[7]);
        z[8]  = fmaf(h, w2.x, z[8]);  z[9]  = fmaf(h, w2.y, z[9]);
        z[10] = fmaf(h, w2.z, z[10]); z[11] = fmaf(h, w2.w, z[11]);
        z[12] = fmaf(h, w3.x, z[12]); z[13] = fmaf(h, w3.y, z[13]);
        z[14] = fmaf(h, w3.z, z[14]); z[15] = fmaf(h, w3.w, z[15]);
      }
      float mx = z[0];
#pragma unroll
      for (int j = 1; j < 16; ++j) mx = fmaxf(mx, z[j]);
      float sum = 0.f;
#pragma unroll
      for (int j = 0; j < 16; ++j) sum += __expf(z[j] - mx);
      float lse = mx + __logf(sum);
      float4* o4 = (float4*)&out[grow * 16];
      o4[0] = make_float4(z[0] - lse, z[1] - lse, z[2] - lse, z[3] - lse);
      o4[1] = make_float4(z[4] - lse, z[5] - lse, z[6] - lse, z[7] - lse);
      o4[2] = make_float4(z[8] - lse, z[9] - lse, z[10] - lse, z[11] - lse);
      o4[3] = make_float4(z[12] - lse, z[13] - lse, z[14] - lse, z[15] - lse);
    }
  }
}

extern "C" void kernel_launch(void* const* d_in, const int* in_sizes, int n_in,
                              void* d_out, int out_size, void* d_ws, size_t ws_size,
                              hipStream_t stream) {
  (void)in_sizes; (void)n_in; (void)out_size; (void)ws_size;
  const float* x   = (const float*)d_in[0];
  const int*   ei  = (const int*)d_in[1];
  const float* W1  = (const float*)d_in[2];
  const float* b1  = (const float*)d_in[3];
  const float* W2  = (const float*)d_in[4];
  const float* b2  = (const float*)d_in[5];
  const float* W3  = (const float*)d_in[6];
  const float* b3  = (const float*)d_in[7];
  const float* Wf1 = (const float*)d_in[8];
  const float* bf1 = (const float*)d_in[9];
  const float* Wf2 = (const float*)d_in[10];
  const float* bf2 = (const float*)d_in[11];
  const float* Wf3 = (const float*)d_in[12];
  const float* bf3 = (const float*)d_in[13];
  float* outp = (float*)d_out;
  const int* src = ei;
  const int* dst = ei + NE;

  char* ws = (char*)d_ws;
  size_t off = 0;
  auto alloc = [&](size_t bytes) { void* p = ws + off; off = (off + bytes + 255) & ~(size_t)255; return p; };
  int*   counts = (int*)alloc((size_t)NN * 4);
  int*   rs     = (int*)alloc((size_t)NN * 4);
  int*   cursor = (int*)alloc((size_t)NN * 4);
  float* dis    = (float*)alloc((size_t)NN * 4);
  int*   blk    = (int*)alloc(128 * 4);
  int*   colidx = (int*)alloc((size_t)NE * 4);
  float* bufA   = (float*)alloc((size_t)NN * 64 * 4);
  float* bufB   = (float*)alloc((size_t)NN * 64 * 4);

  int gN = (NN + 255) / 256;
  int gE = (NE + 255) / 256;
  int NB = (NN + 1023) / 1024;   // 98
  int gMM = (NN + 127) / 128;    // 782
  int gAGG = (NN + 3) / 4;       // 25000

  k_zero<<<gN, 256, 0, stream>>>(counts, NN);
  k_count<<<gE, 256, 0, stream>>>(dst, counts, NE);
  k_dis<<<gN, 256, 0, stream>>>(counts, dis, NN);
  k_scan1<<<NB, 256, 0, stream>>>(counts, rs, blk, NN);
  k_scan2<<<1, 128, 0, stream>>>(blk, NB);
  k_scan3<<<gN, 256, 0, stream>>>(rs, blk, cursor, NN);
  k_fill<<<gE, 256, 0, stream>>>(src, dst, cursor, colidx, NE);

  k_mm<<<gMM, 256, 0, stream>>>(x, W1, dis, bufB, NN);
  k_agg<<<gAGG, 256, 0, stream>>>(bufB, rs, counts, colidx, dis, b1, bufA, NN);
  k_mm<<<gMM, 256, 0, stream>>>(bufA, W2, dis, bufB, NN);
  k_agg<<<gAGG, 256, 0, stream>>>(bufB, rs, counts, colidx, dis, b2, bufA, NN);
  k_mm<<<gMM, 256, 0, stream>>>(bufA, W3, dis, bufB, NN);
  k_agg<<<gAGG, 256, 0, stream>>>(bufB, rs, counts, colidx, dis, b3, bufA, NN);
  k_dense<<<gMM, 256, 0, stream>>>(bufA, Wf1, bf1, Wf2, bf2, Wf3, bf3, outp, NN);
}

// Round 2
// 331.855 us; speedup vs baseline: 1.2068x; 1.2068x over previous
//
#include <hip/hip_runtime.h>
#include <hip/hip_bf16.h>

#define NN 100000
#define NE 800000

// ---------------- CSR build ----------------
static __global__ __launch_bounds__(256) void k_zero(int* __restrict__ p, int n) {
  int i = blockIdx.x * 256 + threadIdx.x;
  if (i < n) p[i] = 0;
}

static __global__ __launch_bounds__(256) void k_count(const int* __restrict__ dst, int* __restrict__ counts, int ne) {
  int e = blockIdx.x * 256 + threadIdx.x;
  if (e < ne) atomicAdd(&counts[dst[e]], 1);
}

static __global__ __launch_bounds__(256) void k_scan1(const int* __restrict__ counts, int* __restrict__ rs,
                                                      int* __restrict__ blk, int n) {
  __shared__ int sd[256];
  int tid = threadIdx.x;
  int base = blockIdx.x * 1024 + tid * 4;
  int v0 = (base + 0 < n) ? counts[base + 0] : 0;
  int v1 = (base + 1 < n) ? counts[base + 1] : 0;
  int v2 = (base + 2 < n) ? counts[base + 2] : 0;
  int v3 = (base + 3 < n) ? counts[base + 3] : 0;
  int s = v0 + v1 + v2 + v3;
  sd[tid] = s;
  __syncthreads();
  for (int off = 1; off < 256; off <<= 1) {
    int t = (tid >= off) ? sd[tid - off] : 0;
    __syncthreads();
    sd[tid] += t;
    __syncthreads();
  }
  int excl = sd[tid] - s;
  if (base + 0 < n) rs[base + 0] = excl;
  if (base + 1 < n) rs[base + 1] = excl + v0;
  if (base + 2 < n) rs[base + 2] = excl + v0 + v1;
  if (base + 3 < n) rs[base + 3] = excl + v0 + v1 + v2;
  if (tid == 255) blk[blockIdx.x] = sd[255];
}

static __global__ void k_scan2(int* __restrict__ blk, int nb) {
  __shared__ int sd[128];
  int tid = threadIdx.x;
  sd[tid] = (tid < nb) ? blk[tid] : 0;
  __syncthreads();
  if (tid == 0) {
    int run = 0;
    for (int i = 0; i < nb; ++i) { int v = sd[i]; sd[i] = run; run += v; }
  }
  __syncthreads();
  if (tid < nb) blk[tid] = sd[tid];
}

// also computes dis (merged former k_dis)
static __global__ __launch_bounds__(256) void k_scan3(int* __restrict__ rs, const int* __restrict__ blk,
                                                      int* __restrict__ cursor, const int* __restrict__ counts,
                                                      float* __restrict__ dis, int n) {
  int i = blockIdx.x * 256 + threadIdx.x;
  if (i < n) {
    int v = rs[i] + blk[i >> 10];
    rs[i] = v;
    cursor[i] = v;
    dis[i] = 1.0f / sqrtf((float)counts[i] + 1.0f);
  }
}

static __global__ __launch_bounds__(256) void k_fill(const int* __restrict__ src, const int* __restrict__ dst,
                                                     int* __restrict__ cursor, int* __restrict__ col_idx, int ne) {
  int e = blockIdx.x * 256 + threadIdx.x;
  if (e < ne) {
    int d = dst[e];
    int pos = atomicAdd(&cursor[d], 1);
    col_idx[pos] = src[e];
  }
}

// ---------------- tiled 64x64 f32 matmul core ----------------
__device__ __forceinline__ void mm_tile(const float (*At)[132], const float (*Ws)[64],
                                        int r0, int c0, float acc[8][4]) {
#pragma unroll 4
  for (int k = 0; k < 64; ++k) {
    float4 w  = *(const float4*)&Ws[k][c0];
    float4 a0 = *(const float4*)&At[k][r0];
    float4 a1 = *(const float4*)&At[k][r0 + 4];
    float a_[8] = {a0.x, a0.y, a0.z, a0.w, a1.x, a1.y, a1.z, a1.w};
#pragma unroll
    for (int r = 0; r < 8; ++r) {
      acc[r][0] = fmaf(a_[r], w.x, acc[r][0]);
      acc[r][1] = fmaf(a_[r], w.y, acc[r][1]);
      acc[r][2] = fmaf(a_[r], w.z, acc[r][2]);
      acc[r][3] = fmaf(a_[r], w.w, acc[r][3]);
    }
  }
}

__device__ __forceinline__ void load_w(const float* __restrict__ W, float (*Ws)[64], int tid) {
  const float4* W4 = (const float4*)W;
  float4* Ws4 = (float4*)&Ws[0][0];
  Ws4[tid] = W4[tid];
  Ws4[tid + 256] = W4[tid + 256];
  Ws4[tid + 512] = W4[tid + 512];
  Ws4[tid + 768] = W4[tid + 768];
}

__device__ __forceinline__ void load_a_transposed(const float* __restrict__ in, float (*At)[132],
                                                  int row0, int n, int tid) {
#pragma unroll
  for (int i = 0; i < 8; ++i) {
    int idx = tid + 256 * i;      // 0..2047
    int r = idx >> 4, c4 = idx & 15;
    int grow = row0 + r;
    float4 v = make_float4(0.f, 0.f, 0.f, 0.f);
    if (grow < n) v = ((const float4*)in)[grow * 16 + c4];
    At[c4 * 4 + 0][r] = v.x;
    At[c4 * 4 + 1][r] = v.y;
    At[c4 * 4 + 2][r] = v.z;
    At[c4 * 4 + 3][r] = v.w;
  }
}

// ht[i][:] = (in[i][:] @ W) * dis[i]
static __global__ __launch_bounds__(256) void k_mm(const float* __restrict__ in, const float* __restrict__ W,
                                                   const float* __restrict__ dis, float* __restrict__ out, int n) {
  __shared__ float At[64][132];
  __shared__ float Ws[64][64];
  int tid = threadIdx.x;
  int row0 = blockIdx.x * 128;
  load_w(W, Ws, tid);
  load_a_transposed(in, At, row0, n, tid);
  __syncthreads();
  int col_t = tid & 15, row_t = tid >> 4;
  int c0 = col_t * 4, r0 = row_t * 8;
  float acc[8][4] = {};
  mm_tile(At, Ws, r0, c0, acc);
#pragma unroll
  for (int r = 0; r < 8; ++r) {
    int grow = row0 + r0 + r;
    if (grow < n) {
      float s = dis[grow];
      float4 o = make_float4(acc[r][0] * s, acc[r][1] * s, acc[r][2] * s, acc[r][3] * s);
      *(float4*)&out[grow * 64 + c0] = o;
    }
  }
}

// out[i][:] = relu(dis[i] * (ht[i][:] + sum_{s in N(i)} ht[s][:]) + b[:])
// one node per wave; 4 lane-groups of 16 gather 4 different neighbor rows per
// issue (float4/lane = 1 KB per load inst), unroll x2 => 8 rows in flight.
static __global__ __launch_bounds__(256) void k_agg(const float* __restrict__ ht, const int* __restrict__ rs,
                                                    const int* __restrict__ counts, const int* __restrict__ col_idx,
                                                    const float* __restrict__ dis, const float* __restrict__ bias,
                                                    float* __restrict__ out, int n) {
  int gw = (blockIdx.x * 256 + threadIdx.x) >> 6;   // node per wave
  int lane = threadIdx.x & 63;
  if (gw >= n) return;
  int g = lane >> 4;        // edge-slot group 0..3
  int f = lane & 15;        // float4 feature slot 0..15
  const float4* ht4 = (const float4*)ht;
  float4 acc = make_float4(0.f, 0.f, 0.f, 0.f);
  if (g == 0) acc = ht4[(size_t)gw * 16 + f];       // self-loop row
  int beg = rs[gw], cnt = counts[gw];
  for (int base = 0; base < cnt; base += 64) {
    int m = cnt - base; if (m > 64) m = 64;
    int idx = (base + lane < cnt) ? col_idx[beg + base + lane] : 0;
    int nj = (m + 3) >> 2;
    int j = 0;
    for (; j + 1 < nj; j += 2) {
      int s0 = __shfl(idx, (j << 2) + g);
      int s1 = __shfl(idx, ((j + 1) << 2) + g);
      bool v1 = (((j + 1) << 2) + g) < m;           // first 4 always valid here
      float4 r0 = ht4[(size_t)s0 * 16 + f];
      float4 r1 = v1 ? ht4[(size_t)s1 * 16 + f] : make_float4(0.f, 0.f, 0.f, 0.f);
      acc.x += r0.x + r1.x; acc.y += r0.y + r1.y;
      acc.z += r0.z + r1.z; acc.w += r0.w + r1.w;
    }
    for (; j < nj; ++j) {
      if (((j << 2) + g) < m) {
        int s0 = __shfl(idx, (j << 2) + g);
        float4 r0 = ht4[(size_t)s0 * 16 + f];
        acc.x += r0.x; acc.y += r0.y; acc.z += r0.z; acc.w += r0.w;
      } else {
        __shfl(idx, (j << 2) + g);  // keep shfl wave-uniform participation
      }
    }
  }
  // reduce partial sums across the 4 groups
  acc.x += __shfl_xor(acc.x, 16); acc.y += __shfl_xor(acc.y, 16);
  acc.z += __shfl_xor(acc.z, 16); acc.w += __shfl_xor(acc.w, 16);
  acc.x += __shfl_xor(acc.x, 32); acc.y += __shfl_xor(acc.y, 32);
  acc.z += __shfl_xor(acc.z, 32); acc.w += __shfl_xor(acc.w, 32);
  if (g == 0) {
    float s = dis[gw];
    float4 b = ((const float4*)bias)[f];
    float4 o;
    o.x = fmaxf(fmaf(s, acc.x, b.x), 0.f);
    o.y = fmaxf(fmaf(s, acc.y, b.y), 0.f);
    o.z = fmaxf(fmaf(s, acc.z, b.z), 0.f);
    o.w = fmaxf(fmaf(s, acc.w, b.w), 0.f);
    ((float4*)out)[(size_t)gw * 16 + f] = o;
  }
}

// fused: relu(h@Wf1+bf1) -> relu(@Wf2+bf2) -> @Wf3+bf3 -> log_softmax
static __global__ __launch_bounds__(256) void k_dense(const float* __restrict__ in,
    const float* __restrict__ Wf1, const float* __restrict__ bf1,
    const float* __restrict__ Wf2, const float* __restrict__ bf2,
    const float* __restrict__ Wf3, const float* __restrict__ bf3,
    float* __restrict__ out, int n) {
  __shared__ float At[64][132];
  __shared__ float Ws[64][64];
  int tid = threadIdx.x;
  int row0 = blockIdx.x * 128;
  load_w(Wf1, Ws, tid);
  load_a_transposed(in, At, row0, n, tid);
  __syncthreads();
  int col_t = tid & 15, row_t = tid >> 4;
  int c0 = col_t * 4, r0 = row_t * 8;
  float4 b1v = *(const float4*)&bf1[c0];
  float acc[8][4] = {};
  mm_tile(At, Ws, r0, c0, acc);
  __syncthreads();
#pragma unroll
  for (int r = 0; r < 8; ++r) {
    At[c0 + 0][r0 + r] = fmaxf(acc[r][0] + b1v.x, 0.f);
    At[c0 + 1][r0 + r] = fmaxf(acc[r][1] + b1v.y, 0.f);
    At[c0 + 2][r0 + r] = fmaxf(acc[r][2] + b1v.z, 0.f);
    At[c0 + 3][r0 + r] = fmaxf(acc[r][3] + b1v.w, 0.f);
  }
  load_w(Wf2, Ws, tid);
  __syncthreads();
  float4 b2v = *(const float4*)&bf2[c0];
  float acc2[8][4] = {};
  mm_tile(At, Ws, r0, c0, acc2);
  __syncthreads();
#pragma unroll
  for (int r = 0; r < 8; ++r) {
    At[c0 + 0][r0 + r] = fmaxf(acc2[r][0] + b2v.x, 0.f);
    At[c0 + 1][r0 + r] = fmaxf(acc2[r][1] + b2v.y, 0.f);
    At[c0 + 2][r0 + r] = fmaxf(acc2[r][2] + b2v.z, 0.f);
    At[c0 + 3][r0 + r] = fmaxf(acc2[r][3] + b2v.w, 0.f);
  }
  __syncthreads();
  if (tid < 128) {
    int grow = row0 + tid;
    if (grow < n) {
      float z[16];
#pragma unroll
      for (int j = 0; j < 16; ++j) z[j] = bf3[j];
      const float4* W3v = (const float4*)Wf3;
#pragma unroll 4
      for (int k = 0; k < 64; ++k) {
        float h = At[k][tid];
        float4 w0 = W3v[k * 4 + 0];
        float4 w1 = W3v[k * 4 + 1];
        float4 w2 = W3v[k * 4 + 2];
        float4 w3 = W3v[k * 4 + 3];
        z[0]  = fmaf(h, w0.x, z[0]);  z[1]  = fmaf(h, w0.y, z[1]);
        z[2]  = fmaf(h, w0.z, z[2]);  z[3]  = fmaf(h, w0.w, z[3]);
        z[4]  = fmaf(h, w1.x, z[4]);  z[5]  = fmaf(h, w1.y, z[5]);
        z[6]  = fmaf(h, w1.z, z[6]);  z[7]  = fmaf(h, w1.w, z[7]);
        z[8]  = fmaf(h, w2.x, z[8]);  z[9]  = fmaf(h, w2.y, z[9]);
        z[10] = fmaf(h, w2.z, z[10]); z[11] = fmaf(h, w2.w, z[11]);
        z[12] = fmaf(h, w3.x, z[12]); z[13] = fmaf(h, w3.y, z[13]);
        z[14] = fmaf(h, w3.z, z[14]); z[15] = fmaf(h, w3.w, z[15]);
      }
      float mx = z[0];
#pragma unroll
      for (int j = 1; j < 16; ++j) mx = fmaxf(mx, z[j]);
      float sum = 0.f;
#pragma unroll
      for (int j = 0; j < 16; ++j) sum += __expf(z[j] - mx);
      float lse = mx + __logf(sum);
      float4* o4 = (float4*)&out[grow * 16];
      o4[0] = make_float4(z[0] - lse, z[1] - lse, z[2] - lse, z[3] - lse);
      o4[1] = make_float4(z[4] - lse, z[5] - lse, z[6] - lse, z[7] - lse);
      o4[2] = make_float4(z[8] - lse, z[9] - lse, z[10] - lse, z[11] - lse);
      o4[3] = make_float4(z[12] - lse, z[13] - lse, z[14] - lse, z[15] - lse);
    }
  }
}

extern "C" void kernel_launch(void* const* d_in, const int* in_sizes, int n_in,
                              void* d_out, int out_size, void* d_ws, size_t ws_size,
                              hipStream_t stream) {
  (void)in_sizes; (void)n_in; (void)out_size; (void)ws_size;
  const float* x   = (const float*)d_in[0];
  const int*   ei  = (const int*)d_in[1];
  const float* W1  = (const float*)d_in[2];
  const float* b1  = (const float*)d_in[3];
  const float* W2  = (const float*)d_in[4];
  const float* b2  = (const float*)d_in[5];
  const float* W3  = (const float*)d_in[6];
  const float* b3  = (const float*)d_in[7];
  const float* Wf1 = (const float*)d_in[8];
  const float* bf1 = (const float*)d_in[9];
  const float* Wf2 = (const float*)d_in[10];
  const float* bf2 = (const float*)d_in[11];
  const float* Wf3 = (const float*)d_in[12];
  const float* bf3 = (const float*)d_in[13];
  float* outp = (float*)d_out;
  const int* src = ei;
  const int* dst = ei + NE;

  char* ws = (char*)d_ws;
  size_t off = 0;
  auto alloc = [&](size_t bytes) { void* p = ws + off; off = (off + bytes + 255) & ~(size_t)255; return p; };
  int*   counts = (int*)alloc((size_t)NN * 4);
  int*   rs     = (int*)alloc((size_t)NN * 4);
  int*   cursor = (int*)alloc((size_t)NN * 4);
  float* dis    = (float*)alloc((size_t)NN * 4);
  int*   blk    = (int*)alloc(128 * 4);
  int*   colidx = (int*)alloc((size_t)NE * 4);
  float* bufA   = (float*)alloc((size_t)NN * 64 * 4);
  float* bufB   = (float*)alloc((size_t)NN * 64 * 4);

  int gN = (NN + 255) / 256;
  int gE = (NE + 255) / 256;
  int NB = (NN + 1023) / 1024;   // 98
  int gMM = (NN + 127) / 128;    // 782
  int gAGG = (NN + 3) / 4;       // 25000

  k_zero<<<gN, 256, 0, stream>>>(counts, NN);
  k_count<<<gE, 256, 0, stream>>>(dst, counts, NE);
  k_scan1<<<NB, 256, 0, stream>>>(counts, rs, blk, NN);
  k_scan2<<<1, 128, 0, stream>>>(blk, NB);
  k_scan3<<<gN, 256, 0, stream>>>(rs, blk, cursor, counts, dis, NN);
  k_fill<<<gE, 256, 0, stream>>>(src, dst, cursor, colidx, NE);

  k_mm<<<gMM, 256, 0, stream>>>(x, W1, dis, bufB, NN);
  k_agg<<<gAGG, 256, 0, stream>>>(bufB, rs, counts, colidx, dis, b1, bufA, NN);
  k_mm<<<gMM, 256, 0, stream>>>(bufA, W2, dis, bufB, NN);
  k_agg<<<gAGG, 256, 0, stream>>>(bufB, rs, counts, colidx, dis, b2, bufA, NN);
  k_mm<<<gMM, 256, 0, stream>>>(bufA, W3, dis, bufB, NN);
  k_agg<<<gAGG, 256, 0, stream>>>(bufB, rs, counts, colidx, dis, b3, bufA, NN);
  k_dense<<<gMM, 256, 0, stream>>>(bufA, Wf1, bf1, Wf2, bf2, Wf3, bf3, outp, NN);
}

// Round 3
// 258.894 us; speedup vs baseline: 1.5469x; 1.2818x over previous
//
#include <hip/hip_runtime.h>
#include <hip/hip_bf16.h>

#define NN 100000
#define NE 800000
#define EBLK 391        // ceil(NE/2048)
#define NBUK 196        // ceil(NN/512), bucket = dst >> 9
#define GH_STRIDE 392   // padded EBLK

// ---------------- atomic-free CSR build ----------------
// P1: per-edge-block histogram over 196 buckets (LDS atomics only)
static __global__ __launch_bounds__(256) void k_hist(const int* __restrict__ dst, int* __restrict__ ghistT) {
  __shared__ int hist[NBUK];
  int tid = threadIdx.x, blk = blockIdx.x;
  for (int i = tid; i < NBUK; i += 256) hist[i] = 0;
  __syncthreads();
  int base = blk * 2048;
#pragma unroll
  for (int i = 0; i < 8; ++i) {
    int e = base + tid + 256 * i;
    if (e < NE) atomicAdd(&hist[dst[e] >> 9], 1);
  }
  __syncthreads();
  for (int i = tid; i < NBUK; i += 256) ghistT[i * GH_STRIDE + blk] = hist[i];
}

// P2: per bucket, exclusive scan over the 391 block histograms (in place) + bucket total
static __global__ __launch_bounds__(64) void k_gscan(int* __restrict__ ghistT, int* __restrict__ btot) {
  int b = blockIdx.x, lane = threadIdx.x;
  int carry = 0;
#pragma unroll
  for (int c = 0; c < (EBLK + 63) / 64; ++c) {
    int e = c * 64 + lane;
    int v = (e < EBLK) ? ghistT[b * GH_STRIDE + e] : 0;
    int s = v;
    for (int off = 1; off < 64; off <<= 1) {
      int t = __shfl_up(s, off);
      if (lane >= off) s += t;
    }
    if (e < EBLK) ghistT[b * GH_STRIDE + e] = carry + s - v;
    carry += __shfl(s, 63);
  }
  if (lane == 0) btot[b] = carry;
}

// P3: exclusive scan of bucket totals -> bstart[0..NBUK]
static __global__ void k_btot(const int* __restrict__ btot, int* __restrict__ bstart) {
  __shared__ int sd[256];
  int tid = threadIdx.x;
  int v = (tid < NBUK) ? btot[tid] : 0;
  sd[tid] = v;
  __syncthreads();
  for (int off = 1; off < 256; off <<= 1) {
    int t = (tid >= off) ? sd[tid - off] : 0;
    __syncthreads();
    sd[tid] += t;
    __syncthreads();
  }
  if (tid <= NBUK) bstart[tid] = sd[tid] - v;   // v==0 for tid>=NBUK -> bstart[NBUK]=NE
}

// P4: partition (src,dst) pairs into bucket-grouped ebuf; LDS staging for coalesced write-out
static __global__ __launch_bounds__(256) void k_scatter(const int* __restrict__ src, const int* __restrict__ dst,
                                                        const int* __restrict__ ghistT, const int* __restrict__ bstart,
                                                        int2* __restrict__ ebuf) {
  __shared__ int hist[256];
  __shared__ int lstart[256];
  __shared__ int cur[NBUK];
  __shared__ int2 sbuf[2048];
  int tid = threadIdx.x, blk = blockIdx.x;
  hist[tid] = 0;
  __syncthreads();
  int base = blk * 2048;
  int dd[8], ss[8];
#pragma unroll
  for (int i = 0; i < 8; ++i) {
    int e = base + tid + 256 * i;
    if (e < NE) {
      dd[i] = dst[e]; ss[i] = src[e];
      atomicAdd(&hist[dd[i] >> 9], 1);
    } else dd[i] = -1;
  }
  __syncthreads();
  int v = hist[tid];
  lstart[tid] = v;
  __syncthreads();
  for (int off = 1; off < 256; off <<= 1) {
    int t = (tid >= off) ? lstart[tid - off] : 0;
    __syncthreads();
    lstart[tid] += t;
    __syncthreads();
  }
  int excl = lstart[tid] - v;
  __syncthreads();
  lstart[tid] = excl;
  if (tid < NBUK) cur[tid] = 0;
  __syncthreads();
#pragma unroll
  for (int i = 0; i < 8; ++i) {
    if (dd[i] >= 0) {
      int b = dd[i] >> 9;
      int p = atomicAdd(&cur[b], 1);
      sbuf[lstart[b] + p] = make_int2(ss[i], dd[i]);
    }
  }
  __syncthreads();
  int m = NE - base; if (m > 2048) m = 2048;
#pragma unroll
  for (int i = 0; i < 8; ++i) {
    int j = tid + 256 * i;
    if (j < m) {
      int2 e = sbuf[j];
      int b = e.y >> 9;
      int gpos = bstart[b] + ghistT[b * GH_STRIDE + blk] + (j - lstart[b]);
      ebuf[gpos] = e;
    }
  }
}

// P5: per bucket (512 nodes): counts/rs/dis + col_idx via LDS histogram+scan+cursors
static __global__ __launch_bounds__(256) void k_bucket(const int2* __restrict__ ebuf, const int* __restrict__ bstart,
                                                       int* __restrict__ counts, int* __restrict__ rs,
                                                       float* __restrict__ dis, int* __restrict__ col_idx) {
  __shared__ int cnt[512];
  __shared__ int lrs[512];
  __shared__ int sd[256];
  int b = blockIdx.x, tid = threadIdx.x;
  int base_n = b << 9;
  int ebeg = bstart[b], eend = bstart[b + 1];
  int m = eend - ebeg;
  cnt[tid] = 0; cnt[tid + 256] = 0;
  __syncthreads();
  for (int j = tid; j < m; j += 256) atomicAdd(&cnt[ebuf[ebeg + j].y - base_n], 1);
  __syncthreads();
  int v0 = cnt[2 * tid], v1 = cnt[2 * tid + 1];
  int s = v0 + v1;
  sd[tid] = s;
  __syncthreads();
  for (int off = 1; off < 256; off <<= 1) {
    int t = (tid >= off) ? sd[tid - off] : 0;
    __syncthreads();
    sd[tid] += t;
    __syncthreads();
  }
  int excl = sd[tid] - s;
  lrs[2 * tid] = excl;
  lrs[2 * tid + 1] = excl + v0;
  __syncthreads();
  for (int i = tid; i < 512; i += 256) {
    int n = base_n + i;
    if (n < NN) {
      int c = cnt[i];
      counts[n] = c;
      rs[n] = ebeg + lrs[i];
      dis[n] = 1.0f / sqrtf((float)c + 1.0f);
    }
  }
  for (int i = tid; i < 512; i += 256) cnt[i] = lrs[i];  // reuse as cursors
  __syncthreads();
  for (int j = tid; j < m; j += 256) {
    int2 e = ebuf[ebeg + j];
    int p = atomicAdd(&cnt[e.y - base_n], 1);
    col_idx[ebeg + p] = e.x;
  }
}

// ---------------- tiled 64x64 f32 matmul (128-row blocks) ----------------
__device__ __forceinline__ void mm_tile(const float (*At)[132], const float (*Ws)[64],
                                        int r0, int c0, float acc[8][4]) {
#pragma unroll 4
  for (int k = 0; k < 64; ++k) {
    float4 w  = *(const float4*)&Ws[k][c0];
    float4 a0 = *(const float4*)&At[k][r0];
    float4 a1 = *(const float4*)&At[k][r0 + 4];
    float a_[8] = {a0.x, a0.y, a0.z, a0.w, a1.x, a1.y, a1.z, a1.w};
#pragma unroll
    for (int r = 0; r < 8; ++r) {
      acc[r][0] = fmaf(a_[r], w.x, acc[r][0]);
      acc[r][1] = fmaf(a_[r], w.y, acc[r][1]);
      acc[r][2] = fmaf(a_[r], w.z, acc[r][2]);
      acc[r][3] = fmaf(a_[r], w.w, acc[r][3]);
    }
  }
}

__device__ __forceinline__ void load_w(const float* __restrict__ W, float (*Ws)[64], int tid) {
  const float4* W4 = (const float4*)W;
  float4* Ws4 = (float4*)&Ws[0][0];
  Ws4[tid] = W4[tid];
  Ws4[tid + 256] = W4[tid + 256];
  Ws4[tid + 512] = W4[tid + 512];
  Ws4[tid + 768] = W4[tid + 768];
}

__device__ __forceinline__ void load_a_transposed(const float* __restrict__ in, float (*At)[132],
                                                  int row0, int n, int tid) {
#pragma unroll
  for (int i = 0; i < 8; ++i) {
    int idx = tid + 256 * i;
    int r = idx >> 4, c4 = idx & 15;
    int grow = row0 + r;
    float4 v = make_float4(0.f, 0.f, 0.f, 0.f);
    if (grow < n) v = ((const float4*)in)[grow * 16 + c4];
    At[c4 * 4 + 0][r] = v.x;
    At[c4 * 4 + 1][r] = v.y;
    At[c4 * 4 + 2][r] = v.z;
    At[c4 * 4 + 3][r] = v.w;
  }
}

// ht[i][:] = (in[i][:] @ W) * dis[i]
static __global__ __launch_bounds__(256) void k_mm(const float* __restrict__ in, const float* __restrict__ W,
                                                   const float* __restrict__ dis, float* __restrict__ out, int n) {
  __shared__ float At[64][132];
  __shared__ float Ws[64][64];
  int tid = threadIdx.x;
  int row0 = blockIdx.x * 128;
  load_w(W, Ws, tid);
  load_a_transposed(in, At, row0, n, tid);
  __syncthreads();
  int col_t = tid & 15, row_t = tid >> 4;
  int c0 = col_t * 4, r0 = row_t * 8;
  float acc[8][4] = {};
  mm_tile(At, Ws, r0, c0, acc);
#pragma unroll
  for (int r = 0; r < 8; ++r) {
    int grow = row0 + r0 + r;
    if (grow < n) {
      float s = dis[grow];
      float4 o = make_float4(acc[r][0] * s, acc[r][1] * s, acc[r][2] * s, acc[r][3] * s);
      *(float4*)&out[grow * 64 + c0] = o;
    }
  }
}

// out[i][:] = relu(dis[i] * (ht[i][:] + sum_{s in N(i)} ht[s][:]) + b[:])
static __global__ __launch_bounds__(256) void k_agg(const float* __restrict__ ht, const int* __restrict__ rs,
                                                    const int* __restrict__ counts, const int* __restrict__ col_idx,
                                                    const float* __restrict__ dis, const float* __restrict__ bias,
                                                    float* __restrict__ out, int n) {
  int gw = (blockIdx.x * 256 + threadIdx.x) >> 6;
  int lane = threadIdx.x & 63;
  if (gw >= n) return;
  int g = lane >> 4;
  int f = lane & 15;
  const float4* ht4 = (const float4*)ht;
  float4 acc = make_float4(0.f, 0.f, 0.f, 0.f);
  if (g == 0) acc = ht4[(size_t)gw * 16 + f];
  int beg = rs[gw], cnt = counts[gw];
  for (int base = 0; base < cnt; base += 64) {
    int m = cnt - base; if (m > 64) m = 64;
    int idx = (base + lane < cnt) ? col_idx[beg + base + lane] : 0;
    int nj = (m + 3) >> 2;
    int j = 0;
    for (; j + 1 < nj; j += 2) {
      int s0 = __shfl(idx, (j << 2) + g);
      int s1 = __shfl(idx, ((j + 1) << 2) + g);
      bool v1 = (((j + 1) << 2) + g) < m;
      float4 r0 = ht4[(size_t)s0 * 16 + f];
      float4 r1 = v1 ? ht4[(size_t)s1 * 16 + f] : make_float4(0.f, 0.f, 0.f, 0.f);
      acc.x += r0.x + r1.x; acc.y += r0.y + r1.y;
      acc.z += r0.z + r1.z; acc.w += r0.w + r1.w;
    }
    for (; j < nj; ++j) {
      if (((j << 2) + g) < m) {
        int s0 = __shfl(idx, (j << 2) + g);
        float4 r0 = ht4[(size_t)s0 * 16 + f];
        acc.x += r0.x; acc.y += r0.y; acc.z += r0.z; acc.w += r0.w;
      } else {
        __shfl(idx, (j << 2) + g);
      }
    }
  }
  acc.x += __shfl_xor(acc.x, 16); acc.y += __shfl_xor(acc.y, 16);
  acc.z += __shfl_xor(acc.z, 16); acc.w += __shfl_xor(acc.w, 16);
  acc.x += __shfl_xor(acc.x, 32); acc.y += __shfl_xor(acc.y, 32);
  acc.z += __shfl_xor(acc.z, 32); acc.w += __shfl_xor(acc.w, 32);
  if (g == 0) {
    float s = dis[gw];
    float4 b = ((const float4*)bias)[f];
    float4 o;
    o.x = fmaxf(fmaf(s, acc.x, b.x), 0.f);
    o.y = fmaxf(fmaf(s, acc.y, b.y), 0.f);
    o.z = fmaxf(fmaf(s, acc.z, b.z), 0.f);
    o.w = fmaxf(fmaf(s, acc.w, b.w), 0.f);
    ((float4*)out)[(size_t)gw * 16 + f] = o;
  }
}

// fused MLP head: 64 rows/block, Wf3 staged in LDS, all-thread z-phase
static __global__ __launch_bounds__(256) void k_dense(const float* __restrict__ in,
    const float* __restrict__ Wf1, const float* __restrict__ bf1,
    const float* __restrict__ Wf2, const float* __restrict__ bf2,
    const float* __restrict__ Wf3, const float* __restrict__ bf3,
    float* __restrict__ out, int n) {
  __shared__ float At[64][68];
  __shared__ float Ws[64][64];
  int tid = threadIdx.x;
  int row0 = blockIdx.x * 64;
  load_w(Wf1, Ws, tid);
#pragma unroll
  for (int i = 0; i < 4; ++i) {
    int idx = tid + 256 * i;          // 0..1023
    int r = idx >> 4, c4 = idx & 15;
    int grow = row0 + r;
    float4 v = make_float4(0.f, 0.f, 0.f, 0.f);
    if (grow < n) v = ((const float4*)in)[grow * 16 + c4];
    At[c4 * 4 + 0][r] = v.x;
    At[c4 * 4 + 1][r] = v.y;
    At[c4 * 4 + 2][r] = v.z;
    At[c4 * 4 + 3][r] = v.w;
  }
  __syncthreads();
  int f = tid & 15, t = tid >> 4;
  int c0 = f * 4, r0 = t * 4;
  float4 b1v = *(const float4*)&bf1[c0];
  float acc[4][4] = {};
#pragma unroll 4
  for (int k = 0; k < 64; ++k) {
    float4 w = *(const float4*)&Ws[k][c0];
    float4 a = *(const float4*)&At[k][r0];
    float a_[4] = {a.x, a.y, a.z, a.w};
#pragma unroll
    for (int r = 0; r < 4; ++r) {
      acc[r][0] = fmaf(a_[r], w.x, acc[r][0]);
      acc[r][1] = fmaf(a_[r], w.y, acc[r][1]);
      acc[r][2] = fmaf(a_[r], w.z, acc[r][2]);
      acc[r][3] = fmaf(a_[r], w.w, acc[r][3]);
    }
  }
  __syncthreads();
#pragma unroll
  for (int r = 0; r < 4; ++r) {
    At[c0 + 0][r0 + r] = fmaxf(acc[r][0] + b1v.x, 0.f);
    At[c0 + 1][r0 + r] = fmaxf(acc[r][1] + b1v.y, 0.f);
    At[c0 + 2][r0 + r] = fmaxf(acc[r][2] + b1v.z, 0.f);
    At[c0 + 3][r0 + r] = fmaxf(acc[r][3] + b1v.w, 0.f);
  }
  load_w(Wf2, Ws, tid);
  __syncthreads();
  float4 b2v = *(const float4*)&bf2[c0];
  float acc2[4][4] = {};
#pragma unroll 4
  for (int k = 0; k < 64; ++k) {
    float4 w = *(const float4*)&Ws[k][c0];
    float4 a = *(const float4*)&At[k][r0];
    float a_[4] = {a.x, a.y, a.z, a.w};
#pragma unroll
    for (int r = 0; r < 4; ++r) {
      acc2[r][0] = fmaf(a_[r], w.x, acc2[r][0]);
      acc2[r][1] = fmaf(a_[r], w.y, acc2[r][1]);
      acc2[r][2] = fmaf(a_[r], w.z, acc2[r][2]);
      acc2[r][3] = fmaf(a_[r], w.w, acc2[r][3]);
    }
  }
  __syncthreads();
#pragma unroll
  for (int r = 0; r < 4; ++r) {
    At[c0 + 0][r0 + r] = fmaxf(acc2[r][0] + b2v.x, 0.f);
    At[c0 + 1][r0 + r] = fmaxf(acc2[r][1] + b2v.y, 0.f);
    At[c0 + 2][r0 + r] = fmaxf(acc2[r][2] + b2v.z, 0.f);
    At[c0 + 3][r0 + r] = fmaxf(acc2[r][3] + b2v.w, 0.f);
  }
  ((float4*)&Ws[0][0])[tid] = ((const float4*)Wf3)[tid];   // Wf3: 64x16 = 4KB
  __syncthreads();
  // z-phase: 4 threads per row, k interleaved mod 4
  int row = tid >> 2, q = tid & 3;
  int grow = row0 + row;
  const float* W3f = &Ws[0][0];
  float z[16];
#pragma unroll
  for (int j = 0; j < 16; ++j) z[j] = 0.f;
#pragma unroll 4
  for (int kk = 0; kk < 16; ++kk) {
    int k = kk * 4 + q;
    float h = At[k][row];
    const float4* w4 = (const float4*)&W3f[k * 16];
    float4 w0 = w4[0], w1 = w4[1], w2 = w4[2], w3 = w4[3];
    z[0]  = fmaf(h, w0.x, z[0]);  z[1]  = fmaf(h, w0.y, z[1]);
    z[2]  = fmaf(h, w0.z, z[2]);  z[3]  = fmaf(h, w0.w, z[3]);
    z[4]  = fmaf(h, w1.x, z[4]);  z[5]  = fmaf(h, w1.y, z[5]);
    z[6]  = fmaf(h, w1.z, z[6]);  z[7]  = fmaf(h, w1.w, z[7]);
    z[8]  = fmaf(h, w2.x, z[8]);  z[9]  = fmaf(h, w2.y, z[9]);
    z[10] = fmaf(h, w2.z, z[10]); z[11] = fmaf(h, w2.w, z[11]);
    z[12] = fmaf(h, w3.x, z[12]); z[13] = fmaf(h, w3.y, z[13]);
    z[14] = fmaf(h, w3.z, z[14]); z[15] = fmaf(h, w3.w, z[15]);
  }
#pragma unroll
  for (int j = 0; j < 16; ++j) {
    z[j] += __shfl_xor(z[j], 1);
    z[j] += __shfl_xor(z[j], 2);
  }
  if (q == 0 && grow < n) {
#pragma unroll
    for (int j = 0; j < 16; ++j) z[j] += bf3[j];
    float mx = z[0];
#pragma unroll
    for (int j = 1; j < 16; ++j) mx = fmaxf(mx, z[j]);
    float sum = 0.f;
#pragma unroll
    for (int j = 0; j < 16; ++j) sum += __expf(z[j] - mx);
    float lse = mx + __logf(sum);
    float4* o4 = (float4*)&out[grow * 16];
    o4[0] = make_float4(z[0] - lse, z[1] - lse, z[2] - lse, z[3] - lse);
    o4[1] = make_float4(z[4] - lse, z[5] - lse, z[6] - lse, z[7] - lse);
    o4[2] = make_float4(z[8] - lse, z[9] - lse, z[10] - lse, z[11] - lse);
    o4[3] = make_float4(z[12] - lse, z[13] - lse, z[14] - lse, z[15] - lse);
  }
}

extern "C" void kernel_launch(void* const* d_in, const int* in_sizes, int n_in,
                              void* d_out, int out_size, void* d_ws, size_t ws_size,
                              hipStream_t stream) {
  (void)in_sizes; (void)n_in; (void)out_size; (void)ws_size;
  const float* x   = (const float*)d_in[0];
  const int*   ei  = (const int*)d_in[1];
  const float* W1  = (const float*)d_in[2];
  const float* b1  = (const float*)d_in[3];
  const float* W2  = (const float*)d_in[4];
  const float* b2  = (const float*)d_in[5];
  const float* W3  = (const float*)d_in[6];
  const float* b3  = (const float*)d_in[7];
  const float* Wf1 = (const float*)d_in[8];
  const float* bf1 = (const float*)d_in[9];
  const float* Wf2 = (const float*)d_in[10];
  const float* bf2 = (const float*)d_in[11];
  const float* Wf3 = (const float*)d_in[12];
  const float* bf3 = (const float*)d_in[13];
  float* outp = (float*)d_out;
  const int* srcp = ei;
  const int* dstp = ei + NE;

  char* ws = (char*)d_ws;
  size_t off = 0;
  auto alloc = [&](size_t bytes) { void* p = ws + off; off = (off + bytes + 255) & ~(size_t)255; return p; };
  int*   counts = (int*)alloc((size_t)NN * 4);
  int*   rs     = (int*)alloc((size_t)NN * 4);
  float* dis    = (float*)alloc((size_t)NN * 4);
  int*   colidx = (int*)alloc((size_t)NE * 4);
  int*   ghistT = (int*)alloc((size_t)NBUK * GH_STRIDE * 4);
  int*   btot   = (int*)alloc(256 * 4);
  int*   bstart = (int*)alloc(256 * 4);
  float* bufA   = (float*)alloc((size_t)NN * 64 * 4);
  float* bufB   = (float*)alloc((size_t)NN * 64 * 4);
  int2*  ebuf   = (int2*)bufB;   // ebuf (6.4MB) dead before first k_mm writes bufB

  int gMM = (NN + 127) / 128;    // 782
  int gAGG = (NN + 3) / 4;       // 25000
  int gDN = (NN + 63) / 64;      // 1563

  k_hist<<<EBLK, 256, 0, stream>>>(dstp, ghistT);
  k_gscan<<<NBUK, 64, 0, stream>>>(ghistT, btot);
  k_btot<<<1, 256, 0, stream>>>(btot, bstart);
  k_scatter<<<EBLK, 256, 0, stream>>>(srcp, dstp, ghistT, bstart, ebuf);
  k_bucket<<<NBUK, 256, 0, stream>>>(ebuf, bstart, counts, rs, dis, colidx);

  k_mm<<<gMM, 256, 0, stream>>>(x, W1, dis, bufB, NN);
  k_agg<<<gAGG, 256, 0, stream>>>(bufB, rs, counts, colidx, dis, b1, bufA, NN);
  k_mm<<<gMM, 256, 0, stream>>>(bufA, W2, dis, bufB, NN);
  k_agg<<<gAGG, 256, 0, stream>>>(bufB, rs, counts, colidx, dis, b2, bufA, NN);
  k_mm<<<gMM, 256, 0, stream>>>(bufA, W3, dis, bufB, NN);
  k_agg<<<gAGG, 256, 0, stream>>>(bufB, rs, counts, colidx, dis, b3, bufA, NN);
  k_dense<<<gDN, 256, 0, stream>>>(bufA, Wf1, bf1, Wf2, bf2, Wf3, bf3, outp, NN);
}

// Round 4
// 235.112 us; speedup vs baseline: 1.7034x; 1.1012x over previous
//
#include <hip/hip_runtime.h>
#include <hip/hip_bf16.h>

#define NN 100000
#define NE 800000
#define EBLK 391        // ceil(NE/2048)
#define NBUK 196        // ceil(NN/512), bucket = dst >> 9
#define GH_STRIDE 392   // padded EBLK

typedef __attribute__((ext_vector_type(8))) short bf16x8;
typedef __attribute__((ext_vector_type(4))) float f32x4;

__device__ __forceinline__ unsigned short f2b(float f) {
  unsigned int x = __float_as_uint(f);
  return (unsigned short)((x + 0x7fffu + ((x >> 16) & 1u)) >> 16);
}

// ---------------- atomic-free CSR build ----------------
static __global__ __launch_bounds__(256) void k_hist(const int* __restrict__ dst, int* __restrict__ ghistT) {
  __shared__ int hist[NBUK];
  int tid = threadIdx.x, blk = blockIdx.x;
  for (int i = tid; i < NBUK; i += 256) hist[i] = 0;
  __syncthreads();
  int base = blk * 2048;
#pragma unroll
  for (int i = 0; i < 8; ++i) {
    int e = base + tid + 256 * i;
    if (e < NE) atomicAdd(&hist[dst[e] >> 9], 1);
  }
  __syncthreads();
  for (int i = tid; i < NBUK; i += 256) ghistT[i * GH_STRIDE + blk] = hist[i];
}

static __global__ __launch_bounds__(64) void k_gscan(int* __restrict__ ghistT, int* __restrict__ btot) {
  int b = blockIdx.x, lane = threadIdx.x;
  int carry = 0;
#pragma unroll
  for (int c = 0; c < (EBLK + 63) / 64; ++c) {
    int e = c * 64 + lane;
    int v = (e < EBLK) ? ghistT[b * GH_STRIDE + e] : 0;
    int s = v;
    for (int off = 1; off < 64; off <<= 1) {
      int t = __shfl_up(s, off);
      if (lane >= off) s += t;
    }
    if (e < EBLK) ghistT[b * GH_STRIDE + e] = carry + s - v;
    carry += __shfl(s, 63);
  }
  if (lane == 0) btot[b] = carry;
}

static __global__ void k_btot(const int* __restrict__ btot, int* __restrict__ bstart) {
  __shared__ int sd[256];
  int tid = threadIdx.x;
  int v = (tid < NBUK) ? btot[tid] : 0;
  sd[tid] = v;
  __syncthreads();
  for (int off = 1; off < 256; off <<= 1) {
    int t = (tid >= off) ? sd[tid - off] : 0;
    __syncthreads();
    sd[tid] += t;
    __syncthreads();
  }
  if (tid <= NBUK) bstart[tid] = sd[tid] - v;
}

static __global__ __launch_bounds__(256) void k_scatter(const int* __restrict__ src, const int* __restrict__ dst,
                                                        const int* __restrict__ ghistT, const int* __restrict__ bstart,
                                                        int2* __restrict__ ebuf) {
  __shared__ int hist[256];
  __shared__ int lstart[256];
  __shared__ int cur[NBUK];
  __shared__ int2 sbuf[2048];
  int tid = threadIdx.x, blk = blockIdx.x;
  hist[tid] = 0;
  __syncthreads();
  int base = blk * 2048;
  int dd[8], ss[8];
#pragma unroll
  for (int i = 0; i < 8; ++i) {
    int e = base + tid + 256 * i;
    if (e < NE) {
      dd[i] = dst[e]; ss[i] = src[e];
      atomicAdd(&hist[dd[i] >> 9], 1);
    } else dd[i] = -1;
  }
  __syncthreads();
  int v = hist[tid];
  lstart[tid] = v;
  __syncthreads();
  for (int off = 1; off < 256; off <<= 1) {
    int t = (tid >= off) ? lstart[tid - off] : 0;
    __syncthreads();
    lstart[tid] += t;
    __syncthreads();
  }
  int excl = lstart[tid] - v;
  __syncthreads();
  lstart[tid] = excl;
  if (tid < NBUK) cur[tid] = 0;
  __syncthreads();
#pragma unroll
  for (int i = 0; i < 8; ++i) {
    if (dd[i] >= 0) {
      int b = dd[i] >> 9;
      int p = atomicAdd(&cur[b], 1);
      sbuf[lstart[b] + p] = make_int2(ss[i], dd[i]);
    }
  }
  __syncthreads();
  int m = NE - base; if (m > 2048) m = 2048;
#pragma unroll
  for (int i = 0; i < 8; ++i) {
    int j = tid + 256 * i;
    if (j < m) {
      int2 e = sbuf[j];
      int b = e.y >> 9;
      int gpos = bstart[b] + ghistT[b * GH_STRIDE + blk] + (j - lstart[b]);
      ebuf[gpos] = e;
    }
  }
}

static __global__ __launch_bounds__(256) void k_bucket(const int2* __restrict__ ebuf, const int* __restrict__ bstart,
                                                       int* __restrict__ counts, int* __restrict__ rs,
                                                       float* __restrict__ dis, int* __restrict__ col_idx) {
  __shared__ int cnt[512];
  __shared__ int lrs[512];
  __shared__ int sd[256];
  int b = blockIdx.x, tid = threadIdx.x;
  int base_n = b << 9;
  int ebeg = bstart[b], eend = bstart[b + 1];
  int m = eend - ebeg;
  cnt[tid] = 0; cnt[tid + 256] = 0;
  __syncthreads();
  for (int j = tid; j < m; j += 256) atomicAdd(&cnt[ebuf[ebeg + j].y - base_n], 1);
  __syncthreads();
  int v0 = cnt[2 * tid], v1 = cnt[2 * tid + 1];
  int s = v0 + v1;
  sd[tid] = s;
  __syncthreads();
  for (int off = 1; off < 256; off <<= 1) {
    int t = (tid >= off) ? sd[tid - off] : 0;
    __syncthreads();
    sd[tid] += t;
    __syncthreads();
  }
  int excl = sd[tid] - s;
  lrs[2 * tid] = excl;
  lrs[2 * tid + 1] = excl + v0;
  __syncthreads();
  for (int i = tid; i < 512; i += 256) {
    int n = base_n + i;
    if (n < NN) {
      int c = cnt[i];
      counts[n] = c;
      rs[n] = ebeg + lrs[i];
      dis[n] = 1.0f / sqrtf((float)c + 1.0f);
    }
  }
  for (int i = tid; i < 512; i += 256) cnt[i] = lrs[i];
  __syncthreads();
  for (int j = tid; j < m; j += 256) {
    int2 e = ebuf[ebeg + j];
    int p = atomicAdd(&cnt[e.y - base_n], 1);
    col_idx[ebeg + p] = e.x;
  }
}

// ---------------- weight convert + transpose to bf16 ----------------
// Wt[n][k] (bf16) so B-fragments are 16B-contiguous: lane l -> col=l&15, k=(l>>4)*8+j
static __global__ __launch_bounds__(256) void k_wconv(
    const float* __restrict__ W1, const float* __restrict__ W2, const float* __restrict__ W3,
    const float* __restrict__ Wf1, const float* __restrict__ Wf2, const float* __restrict__ Wf3,
    short* __restrict__ W1t, short* __restrict__ W2t, short* __restrict__ W3t,
    short* __restrict__ Wf1t, short* __restrict__ Wf2t, short* __restrict__ Wf3t) {
  int b = blockIdx.x, tid = threadIdx.x;
  if (b < 5) {
    const float* W = (b == 0) ? W1 : (b == 1) ? W2 : (b == 2) ? W3 : (b == 3) ? Wf1 : Wf2;
    short* Wt = (b == 0) ? W1t : (b == 1) ? W2t : (b == 2) ? W3t : (b == 3) ? Wf1t : Wf2t;
#pragma unroll
    for (int i = 0; i < 16; ++i) {
      int idx = tid + 256 * i;       // = k*64 + n
      int k = idx >> 6, nn = idx & 63;
      Wt[nn * 64 + k] = (short)f2b(W[idx]);
    }
  } else {
#pragma unroll
    for (int i = 0; i < 4; ++i) {
      int idx = tid + 256 * i;       // = k*16 + n
      int k = idx >> 4, nn = idx & 15;
      Wf3t[nn * 64 + k] = (short)f2b(Wf3[idx]);
    }
  }
}

__device__ __forceinline__ bf16x8 load_a_frag(const float* __restrict__ p, bool valid) {
  float4 f0 = valid ? *(const float4*)p : make_float4(0.f, 0.f, 0.f, 0.f);
  float4 f1 = valid ? *(const float4*)(p + 4) : make_float4(0.f, 0.f, 0.f, 0.f);
  bf16x8 a;
  a[0] = (short)f2b(f0.x); a[1] = (short)f2b(f0.y); a[2] = (short)f2b(f0.z); a[3] = (short)f2b(f0.w);
  a[4] = (short)f2b(f1.x); a[5] = (short)f2b(f1.y); a[6] = (short)f2b(f1.z); a[7] = (short)f2b(f1.w);
  return a;
}

// ht[i][:] = (in[i][:] @ W) * dis[i]   -- MFMA, no LDS, no barriers
static __global__ __launch_bounds__(256) void k_mm(const float* __restrict__ in, const short* __restrict__ Wt,
                                                   const float* __restrict__ dis, float* __restrict__ out, int n) {
  int tid = threadIdx.x;
  int lane = tid & 63, w = tid >> 6;
  int row0 = blockIdx.x * 64 + w * 16;
  int rlane = lane & 15, g = lane >> 4;
  int arow = row0 + rlane;
  bool av = arow < n;
  const float* ap = in + (size_t)arow * 64 + g * 8;
  bf16x8 a0 = load_a_frag(ap, av);
  bf16x8 a1 = load_a_frag(ap + 32, av);
  f32x4 acc[4];
#pragma unroll
  for (int t = 0; t < 4; ++t) acc[t] = (f32x4){0.f, 0.f, 0.f, 0.f};
#pragma unroll
  for (int t = 0; t < 4; ++t) {
    bf16x8 b0 = *(const bf16x8*)(Wt + (rlane + 16 * t) * 64 + g * 8);
    bf16x8 b1 = *(const bf16x8*)(Wt + (rlane + 16 * t) * 64 + g * 8 + 32);
    acc[t] = __builtin_amdgcn_mfma_f32_16x16x32_bf16(a0, b0, acc[t], 0, 0, 0);
    acc[t] = __builtin_amdgcn_mfma_f32_16x16x32_bf16(a1, b1, acc[t], 0, 0, 0);
  }
  // D: row = row0 + g*4 + r, col = rlane + 16t
#pragma unroll
  for (int r = 0; r < 4; ++r) {
    int gr = row0 + g * 4 + r;
    if (gr < n) {
      float s = dis[gr];
#pragma unroll
      for (int t = 0; t < 4; ++t)
        out[(size_t)gr * 64 + rlane + 16 * t] = acc[t][r] * s;
    }
  }
}

// out[i][:] = relu(dis[i] * (ht[i][:] + sum_{s in N(i)} ht[s][:]) + b[:])
static __global__ __launch_bounds__(256) void k_agg(const float* __restrict__ ht, const int* __restrict__ rs,
                                                    const int* __restrict__ counts, const int* __restrict__ col_idx,
                                                    const float* __restrict__ dis, const float* __restrict__ bias,
                                                    float* __restrict__ out, int n) {
  int gw = (blockIdx.x * 256 + threadIdx.x) >> 6;
  int lane = threadIdx.x & 63;
  if (gw >= n) return;
  int g = lane >> 4;
  int f = lane & 15;
  const float4* ht4 = (const float4*)ht;
  float4 acc = make_float4(0.f, 0.f, 0.f, 0.f);
  if (g == 0) acc = ht4[(size_t)gw * 16 + f];
  int beg = rs[gw], cnt = counts[gw];
  for (int base = 0; base < cnt; base += 64) {
    int m = cnt - base; if (m > 64) m = 64;
    int idx = (base + lane < cnt) ? col_idx[beg + base + lane] : 0;
    int nj = (m + 3) >> 2;
    int j = 0;
    for (; j + 1 < nj; j += 2) {
      int s0 = __shfl(idx, (j << 2) + g);
      int s1 = __shfl(idx, ((j + 1) << 2) + g);
      bool v1 = (((j + 1) << 2) + g) < m;
      float4 r0 = ht4[(size_t)s0 * 16 + f];
      float4 r1 = v1 ? ht4[(size_t)s1 * 16 + f] : make_float4(0.f, 0.f, 0.f, 0.f);
      acc.x += r0.x + r1.x; acc.y += r0.y + r1.y;
      acc.z += r0.z + r1.z; acc.w += r0.w + r1.w;
    }
    for (; j < nj; ++j) {
      if (((j << 2) + g) < m) {
        int s0 = __shfl(idx, (j << 2) + g);
        float4 r0 = ht4[(size_t)s0 * 16 + f];
        acc.x += r0.x; acc.y += r0.y; acc.z += r0.z; acc.w += r0.w;
      } else {
        __shfl(idx, (j << 2) + g);
      }
    }
  }
  acc.x += __shfl_xor(acc.x, 16); acc.y += __shfl_xor(acc.y, 16);
  acc.z += __shfl_xor(acc.z, 16); acc.w += __shfl_xor(acc.w, 16);
  acc.x += __shfl_xor(acc.x, 32); acc.y += __shfl_xor(acc.y, 32);
  acc.z += __shfl_xor(acc.z, 32); acc.w += __shfl_xor(acc.w, 32);
  if (g == 0) {
    float s = dis[gw];
    float4 b = ((const float4*)bias)[f];
    float4 o;
    o.x = fmaxf(fmaf(s, acc.x, b.x), 0.f);
    o.y = fmaxf(fmaf(s, acc.y, b.y), 0.f);
    o.z = fmaxf(fmaf(s, acc.z, b.z), 0.f);
    o.w = fmaxf(fmaf(s, acc.w, b.w), 0.f);
    ((float4*)out)[(size_t)gw * 16 + f] = o;
  }
}

// fused MLP head: 3 MFMA layers, per-wave-private LDS stripe, no barriers
static __global__ __launch_bounds__(256) void k_dense(const float* __restrict__ in,
    const short* __restrict__ W1t, const float* __restrict__ bf1,
    const short* __restrict__ W2t, const float* __restrict__ bf2,
    const short* __restrict__ W3t, const float* __restrict__ bf3,
    float* __restrict__ out, int n) {
  __shared__ __align__(16) short Hs[4][16][72];   // per-wave 16 rows x 64 bf16 (+8 pad)
  int tid = threadIdx.x;
  int lane = tid & 63, w = tid >> 6;
  int row0 = blockIdx.x * 64 + w * 16;
  int rlane = lane & 15, g = lane >> 4;
  int arow = row0 + rlane;
  bool av = arow < n;
  const float* ap = in + (size_t)arow * 64 + g * 8;
  bf16x8 a0 = load_a_frag(ap, av);
  bf16x8 a1 = load_a_frag(ap + 32, av);
  f32x4 acc[4];
#pragma unroll
  for (int t = 0; t < 4; ++t) acc[t] = (f32x4){0.f, 0.f, 0.f, 0.f};
#pragma unroll
  for (int t = 0; t < 4; ++t) {
    bf16x8 b0 = *(const bf16x8*)(W1t + (rlane + 16 * t) * 64 + g * 8);
    bf16x8 b1 = *(const bf16x8*)(W1t + (rlane + 16 * t) * 64 + g * 8 + 32);
    acc[t] = __builtin_amdgcn_mfma_f32_16x16x32_bf16(a0, b0, acc[t], 0, 0, 0);
    acc[t] = __builtin_amdgcn_mfma_f32_16x16x32_bf16(a1, b1, acc[t], 0, 0, 0);
  }
  // relu + bf1 -> Hs (each wave touches only Hs[w])
#pragma unroll
  for (int t = 0; t < 4; ++t) {
    float bb = bf1[16 * t + rlane];
#pragma unroll
    for (int r = 0; r < 4; ++r)
      Hs[w][g * 4 + r][16 * t + rlane] = (short)f2b(fmaxf(acc[t][r] + bb, 0.f));
  }
  bf16x8 c0 = *(const bf16x8*)&Hs[w][rlane][g * 8];
  bf16x8 c1 = *(const bf16x8*)&Hs[w][rlane][g * 8 + 32];
  f32x4 acc2[4];
#pragma unroll
  for (int t = 0; t < 4; ++t) acc2[t] = (f32x4){0.f, 0.f, 0.f, 0.f};
#pragma unroll
  for (int t = 0; t < 4; ++t) {
    bf16x8 b0 = *(const bf16x8*)(W2t + (rlane + 16 * t) * 64 + g * 8);
    bf16x8 b1 = *(const bf16x8*)(W2t + (rlane + 16 * t) * 64 + g * 8 + 32);
    acc2[t] = __builtin_amdgcn_mfma_f32_16x16x32_bf16(c0, b0, acc2[t], 0, 0, 0);
    acc2[t] = __builtin_amdgcn_mfma_f32_16x16x32_bf16(c1, b1, acc2[t], 0, 0, 0);
  }
#pragma unroll
  for (int t = 0; t < 4; ++t) {
    float bb = bf2[16 * t + rlane];
#pragma unroll
    for (int r = 0; r < 4; ++r)
      Hs[w][g * 4 + r][16 * t + rlane] = (short)f2b(fmaxf(acc2[t][r] + bb, 0.f));
  }
  bf16x8 d0 = *(const bf16x8*)&Hs[w][rlane][g * 8];
  bf16x8 d1 = *(const bf16x8*)&Hs[w][rlane][g * 8 + 32];
  bf16x8 e0 = *(const bf16x8*)(W3t + rlane * 64 + g * 8);
  bf16x8 e1 = *(const bf16x8*)(W3t + rlane * 64 + g * 8 + 32);
  f32x4 z = (f32x4){0.f, 0.f, 0.f, 0.f};
  z = __builtin_amdgcn_mfma_f32_16x16x32_bf16(d0, e0, z, 0, 0, 0);
  z = __builtin_amdgcn_mfma_f32_16x16x32_bf16(d1, e1, z, 0, 0, 0);
  // z[r]: logits of row (row0 + g*4 + r), class = rlane; softmax across 16 lanes
  float bsc = bf3[rlane];
#pragma unroll
  for (int r = 0; r < 4; ++r) {
    float zz = z[r] + bsc;
    float mx = zz;
    mx = fmaxf(mx, __shfl_xor(mx, 1));
    mx = fmaxf(mx, __shfl_xor(mx, 2));
    mx = fmaxf(mx, __shfl_xor(mx, 4));
    mx = fmaxf(mx, __shfl_xor(mx, 8));
    float ex = __expf(zz - mx);
    ex += __shfl_xor(ex, 1);
    ex += __shfl_xor(ex, 2);
    ex += __shfl_xor(ex, 4);
    ex += __shfl_xor(ex, 8);
    float lse = mx + __logf(ex);
    int gr = row0 + g * 4 + r;
    if (gr < n) out[(size_t)gr * 16 + rlane] = zz - lse;
  }
}

extern "C" void kernel_launch(void* const* d_in, const int* in_sizes, int n_in,
                              void* d_out, int out_size, void* d_ws, size_t ws_size,
                              hipStream_t stream) {
  (void)in_sizes; (void)n_in; (void)out_size; (void)ws_size;
  const float* x   = (const float*)d_in[0];
  const int*   ei  = (const int*)d_in[1];
  const float* W1  = (const float*)d_in[2];
  const float* b1  = (const float*)d_in[3];
  const float* W2  = (const float*)d_in[4];
  const float* b2  = (const float*)d_in[5];
  const float* W3  = (const float*)d_in[6];
  const float* b3  = (const float*)d_in[7];
  const float* Wf1 = (const float*)d_in[8];
  const float* bf1 = (const float*)d_in[9];
  const float* Wf2 = (const float*)d_in[10];
  const float* bf2 = (const float*)d_in[11];
  const float* Wf3 = (const float*)d_in[12];
  const float* bf3 = (const float*)d_in[13];
  float* outp = (float*)d_out;
  const int* srcp = ei;
  const int* dstp = ei + NE;

  char* ws = (char*)d_ws;
  size_t off = 0;
  auto alloc = [&](size_t bytes) { void* p = ws + off; off = (off + bytes + 255) & ~(size_t)255; return p; };
  int*   counts = (int*)alloc((size_t)NN * 4);
  int*   rs     = (int*)alloc((size_t)NN * 4);
  float* dis    = (float*)alloc((size_t)NN * 4);
  int*   colidx = (int*)alloc((size_t)NE * 4);
  int*   ghistT = (int*)alloc((size_t)NBUK * GH_STRIDE * 4);
  int*   btot   = (int*)alloc(256 * 4);
  int*   bstart = (int*)alloc(256 * 4);
  short* W1t    = (short*)alloc(4096 * 2);
  short* W2t    = (short*)alloc(4096 * 2);
  short* W3t    = (short*)alloc(4096 * 2);
  short* Wf1t   = (short*)alloc(4096 * 2);
  short* Wf2t   = (short*)alloc(4096 * 2);
  short* Wf3t   = (short*)alloc(1024 * 2);
  float* bufA   = (float*)alloc((size_t)NN * 64 * 4);
  float* bufB   = (float*)alloc((size_t)NN * 64 * 4);
  int2*  ebuf   = (int2*)bufB;   // ebuf (6.4MB) dead before first k_mm writes bufB

  int gMM = (NN + 63) / 64;      // 1563
  int gAGG = (NN + 3) / 4;       // 25000

  k_wconv<<<6, 256, 0, stream>>>(W1, W2, W3, Wf1, Wf2, Wf3, W1t, W2t, W3t, Wf1t, Wf2t, Wf3t);
  k_hist<<<EBLK, 256, 0, stream>>>(dstp, ghistT);
  k_gscan<<<NBUK, 64, 0, stream>>>(ghistT, btot);
  k_btot<<<1, 256, 0, stream>>>(btot, bstart);
  k_scatter<<<EBLK, 256, 0, stream>>>(srcp, dstp, ghistT, bstart, ebuf);
  k_bucket<<<NBUK, 256, 0, stream>>>(ebuf, bstart, counts, rs, dis, colidx);

  k_mm<<<gMM, 256, 0, stream>>>(x, W1t, dis, bufB, NN);
  k_agg<<<gAGG, 256, 0, stream>>>(bufB, rs, counts, colidx, dis, b1, bufA, NN);
  k_mm<<<gMM, 256, 0, stream>>>(bufA, W2t, dis, bufB, NN);
  k_agg<<<gAGG, 256, 0, stream>>>(bufB, rs, counts, colidx, dis, b2, bufA, NN);
  k_mm<<<gMM, 256, 0, stream>>>(bufA, W3t, dis, bufB, NN);
  k_agg<<<gAGG, 256, 0, stream>>>(bufB, rs, counts, colidx, dis, b3, bufA, NN);
  k_dense<<<gMM, 256, 0, stream>>>(bufA, Wf1t, bf1, Wf2t, bf2, Wf3t, bf3, outp, NN);
}